// Round 1
// baseline (803.035 us; speedup 1.0000x reference)
//
#include <hip/hip_runtime.h>
#include <stdint.h>

#define HEADS 8
#define DH    32
#define BSZ   8
#define HALO  3
#define WIN   14
#define NKEY  (WIN*WIN)   // 196
#define NQ    (BSZ*BSZ)   // 64
#define CIN   256
#define IMG   128
#define HWPIX (IMG*IMG)   // 16384
#define MQKV  768         // 256 q + 512 kv channels
#define SCALE 0.17677669529663689f  // 32^-0.5

__device__ __forceinline__ float bflo(unsigned int u){ return __uint_as_float(u << 16); }
__device__ __forceinline__ float bfhi(unsigned int u){ return __uint_as_float(u & 0xffff0000u); }
__device__ __forceinline__ unsigned short f2bf(float f){
  unsigned int u = __float_as_uint(f);
  u += 0x7fffu + ((u >> 16) & 1u);   // RNE
  return (unsigned short)(u >> 16);
}
__device__ __forceinline__ float bf2f(unsigned short s){ return __uint_as_float(((unsigned int)s) << 16); }

// ---------------------------------------------------------------------------
// Phase 1: qkv projection GEMM.  out[p][m] (bf16) = sum_k Wcat[m][k] * x[b][k][p]
// Wcat rows 0..255 = w_q, 256..767 = w_kv.  64x64 tile, 256 threads, 4x4 micro.
// ---------------------------------------------------------------------------
__global__ __launch_bounds__(256, 4)
void proj_kernel(const float* __restrict__ x,     // chunk base: [nb][256][HWPIX]
                 const float* __restrict__ wq,    // [256][256]
                 const float* __restrict__ wkv,   // [512][256]
                 unsigned short* __restrict__ qkv)// [nb*HWPIX][768] bf16
{
  const int p0 = blockIdx.x * 64;          // pixel tile (chunk-local)
  const int m0 = blockIdx.y * 64;          // channel tile
  const int b  = p0 / HWPIX;
  const int pl = p0 % HWPIX;
  const float* wbase = (m0 < CIN) ? (wq + (size_t)m0 * CIN)
                                  : (wkv + (size_t)(m0 - CIN) * CIN);
  const float* xbase = x + (size_t)b * CIN * HWPIX + pl;

  __shared__ __align__(16) float As[32][68];   // [k][m], padded
  __shared__ __align__(16) float Bs[32][64];   // [k][p]

  const int tid = threadIdx.x;
  const int tx = tid & 15;      // m direction (4 outputs)
  const int ty = tid >> 4;      // p direction (4 outputs)

  float acc[4][4];
  #pragma unroll
  for (int i = 0; i < 4; ++i)
    #pragma unroll
    for (int j = 0; j < 4; ++j) acc[i][j] = 0.f;

  for (int k0 = 0; k0 < CIN; k0 += 32) {
    #pragma unroll
    for (int it = 0; it < 2; ++it) {
      int idx = tid + it * 256;
      int r  = idx >> 3;                  // W row (m), 0..63
      int c4 = idx & 7;                   // float4 within k-range
      float4 w4 = *(const float4*)(wbase + (size_t)r * CIN + k0 + c4 * 4);
      As[c4*4+0][r] = w4.x;
      As[c4*4+1][r] = w4.y;
      As[c4*4+2][r] = w4.z;
      As[c4*4+3][r] = w4.w;
      int c  = idx >> 4;                  // x row (k), 0..31
      int p4 = idx & 15;                  // float4 within pixel range
      float4 x4 = *(const float4*)(xbase + (size_t)(k0 + c) * HWPIX + p4 * 4);
      *(float4*)&Bs[c][p4*4] = x4;
    }
    __syncthreads();
    #pragma unroll
    for (int kk = 0; kk < 32; ++kk) {
      float4 a4 = *(const float4*)&As[kk][tx*4];
      float4 b4 = *(const float4*)&Bs[kk][ty*4];
      acc[0][0] = fmaf(a4.x, b4.x, acc[0][0]);
      acc[1][0] = fmaf(a4.y, b4.x, acc[1][0]);
      acc[2][0] = fmaf(a4.z, b4.x, acc[2][0]);
      acc[3][0] = fmaf(a4.w, b4.x, acc[3][0]);
      acc[0][1] = fmaf(a4.x, b4.y, acc[0][1]);
      acc[1][1] = fmaf(a4.y, b4.y, acc[1][1]);
      acc[2][1] = fmaf(a4.z, b4.y, acc[2][1]);
      acc[3][1] = fmaf(a4.w, b4.y, acc[3][1]);
      acc[0][2] = fmaf(a4.x, b4.z, acc[0][2]);
      acc[1][2] = fmaf(a4.y, b4.z, acc[1][2]);
      acc[2][2] = fmaf(a4.z, b4.z, acc[2][2]);
      acc[3][2] = fmaf(a4.w, b4.z, acc[3][2]);
      acc[0][3] = fmaf(a4.x, b4.w, acc[0][3]);
      acc[1][3] = fmaf(a4.y, b4.w, acc[1][3]);
      acc[2][3] = fmaf(a4.z, b4.w, acc[2][3]);
      acc[3][3] = fmaf(a4.w, b4.w, acc[3][3]);
    }
    __syncthreads();
  }

  #pragma unroll
  for (int j = 0; j < 4; ++j) {
    size_t p = (size_t)p0 + ty * 4 + j;
    ushort4 pk;
    pk.x = f2bf(acc[0][j]);
    pk.y = f2bf(acc[1][j]);
    pk.z = f2bf(acc[2][j]);
    pk.w = f2bf(acc[3][j]);
    *(ushort4*)(qkv + p * MQKV + m0 + tx * 4) = pk;
  }
}

// ---------------------------------------------------------------------------
// Phase 2: fused halo attention.  One 256-thread block per (window, head, batch).
// Thread (q,g): q = query 0..63, g = key-phase 0..3 (keys k = g+4t).
// Max-free softmax: p = exp(s) directly (|s| <~ 15, no overflow), partial
// (sum, acc[32]) per thread, quad butterfly reduce, normalize at write.
// ---------------------------------------------------------------------------
__global__ __launch_bounds__(256, 3)
void attn_kernel(const unsigned short* __restrict__ qkv, // chunk base [nb*HWPIX][768]
                 const float* __restrict__ hrel,         // [27][32]
                 const float* __restrict__ wrel,         // [27][32]
                 float* __restrict__ out,                // [4][256][128][128]
                 int b0)
{
  const int blk = blockIdx.x;            // by*16+bx
  const int hd  = blockIdx.y;
  const int bb  = blockIdx.z;            // chunk-local batch
  const int by = blk >> 4, bx = blk & 15;

  __shared__ __align__(16) unsigned short Ks[NKEY][DH];   // 12544 B
  __shared__ __align__(16) unsigned short Vs[NKEY][DH];   // 12544 B
  __shared__ __align__(16) unsigned short RhS[NQ][WIN];   // 1792 B
  __shared__ __align__(16) unsigned short RwS[NQ][WIN];   // 1792 B
  __shared__ __align__(16) float HrelS[27 * DH];          // 3456 B
  __shared__ __align__(16) float WrelS[27 * DH];          // 3456 B

  const int tid = threadIdx.x;
  const int q = tid >> 2, g = tid & 3;
  const int qy = q >> 3, qx = q & 7;
  const int gy = by * BSZ + qy, gx = bx * BSZ + qx;

  // q row -> registers (fp32)
  float qreg[32];
  {
    const uint4* qp = (const uint4*)(qkv + ((size_t)bb * HWPIX + gy * IMG + gx) * MQKV + hd * DH);
    #pragma unroll
    for (int i = 0; i < 4; ++i) {
      uint4 u = qp[i];
      qreg[i*8+0] = bflo(u.x); qreg[i*8+1] = bfhi(u.x);
      qreg[i*8+2] = bflo(u.y); qreg[i*8+3] = bfhi(u.y);
      qreg[i*8+4] = bflo(u.z); qreg[i*8+5] = bfhi(u.z);
      qreg[i*8+6] = bflo(u.w); qreg[i*8+7] = bfhi(u.w);
    }
  }

  // cooperative K/V window load (zero-pad outside image; padded keys DO
  // participate in softmax with bias-only logits, matching the reference)
  for (int idx = tid; idx < NKEY * 8; idx += 256) {
    int key = idx >> 3, part = idx & 7;    // 8 x uint4 per key (32 k + 32 v bf16)
    int ky = key / WIN, kx = key - ky * WIN;
    int sy = by * BSZ - HALO + ky, sx = bx * BSZ - HALO + kx;
    uint4 val = make_uint4(0u, 0u, 0u, 0u);
    if (sy >= 0 && sy < IMG && sx >= 0 && sx < IMG)
      val = *(const uint4*)(qkv + ((size_t)bb * HWPIX + sy * IMG + sx) * MQKV
                            + CIN + hd * 64 + part * 8);
    unsigned short* dst = (part < 4) ? &Ks[key][part * 8] : &Vs[key][(part - 4) * 8];
    *(uint4*)dst = val;
  }
  // rel tables -> LDS
  for (int idx = tid; idx < 27 * DH; idx += 256) {
    HrelS[idx] = hrel[idx];
    WrelS[idx] = wrel[idx];
  }
  __syncthreads();

  // bias tables: Rh[q][ky] = q . height_rel[ky - qy + 13], Rw likewise with qx
  for (int j = g; j < WIN; j += 4) {
    const float4* hr = (const float4*)&HrelS[(j - qy + (WIN - 1)) * DH];
    const float4* wr = (const float4*)&WrelS[(j - qx + (WIN - 1)) * DH];
    float dh = 0.f, dw = 0.f;
    #pragma unroll
    for (int i = 0; i < 8; ++i) {
      float4 h4 = hr[i], w4 = wr[i];
      dh += qreg[i*4+0]*h4.x + qreg[i*4+1]*h4.y + qreg[i*4+2]*h4.z + qreg[i*4+3]*h4.w;
      dw += qreg[i*4+0]*w4.x + qreg[i*4+1]*w4.y + qreg[i*4+2]*w4.z + qreg[i*4+3]*w4.w;
    }
    RhS[q][j] = f2bf(dh);
    RwS[q][j] = f2bf(dw);
  }
  __syncthreads();

  float acc[DH];
  #pragma unroll
  for (int d = 0; d < DH; ++d) acc[d] = 0.f;
  float lsum = 0.f;

  for (int t = 0; t < 49; ++t) {
    int k = g + 4 * t;
    const uint4* kr = (const uint4*)Ks[k];
    float dot = 0.f;
    #pragma unroll
    for (int i = 0; i < 4; ++i) {
      uint4 u = kr[i];
      dot += bflo(u.x) * qreg[i*8+0] + bfhi(u.x) * qreg[i*8+1]
           + bflo(u.y) * qreg[i*8+2] + bfhi(u.y) * qreg[i*8+3]
           + bflo(u.z) * qreg[i*8+4] + bfhi(u.z) * qreg[i*8+5]
           + bflo(u.w) * qreg[i*8+6] + bfhi(u.w) * qreg[i*8+7];
    }
    int ky = k / WIN, kx = k - ky * WIN;
    float s = dot * SCALE + bf2f(RhS[q][ky]) + bf2f(RwS[q][kx]);
    float p = __expf(s);
    lsum += p;
    const uint4* vr = (const uint4*)Vs[k];
    #pragma unroll
    for (int i = 0; i < 4; ++i) {
      uint4 u = vr[i];
      acc[i*8+0] += p * bflo(u.x); acc[i*8+1] += p * bfhi(u.x);
      acc[i*8+2] += p * bflo(u.y); acc[i*8+3] += p * bfhi(u.y);
      acc[i*8+4] += p * bflo(u.z); acc[i*8+5] += p * bfhi(u.z);
      acc[i*8+6] += p * bflo(u.w); acc[i*8+7] += p * bfhi(u.w);
    }
  }

  // quad butterfly reduce (lanes q*4+g are contiguous within a wave)
  lsum += __shfl_xor(lsum, 1);
  lsum += __shfl_xor(lsum, 2);
  #pragma unroll
  for (int d = 0; d < DH; ++d) {
    acc[d] += __shfl_xor(acc[d], 1);
    acc[d] += __shfl_xor(acc[d], 2);
  }
  float inv = 1.f / lsum;

  // thread g writes dims [g*8, g*8+8) — static-index selection to avoid scratch
  float ov[8];
  if (g == 0) {
    #pragma unroll
    for (int i = 0; i < 8; ++i) ov[i] = acc[i];
  } else if (g == 1) {
    #pragma unroll
    for (int i = 0; i < 8; ++i) ov[i] = acc[8 + i];
  } else if (g == 2) {
    #pragma unroll
    for (int i = 0; i < 8; ++i) ov[i] = acc[16 + i];
  } else {
    #pragma unroll
    for (int i = 0; i < 8; ++i) ov[i] = acc[24 + i];
  }
  float* ob = out + ((size_t)(b0 + bb) * 256 + hd * DH + g * 8) * HWPIX
            + gy * IMG + gx;
  #pragma unroll
  for (int i = 0; i < 8; ++i) ob[(size_t)i * HWPIX] = ov[i] * inv;
}

// ---------------------------------------------------------------------------
extern "C" void kernel_launch(void* const* d_in, const int* in_sizes, int n_in,
                              void* d_out, int out_size, void* d_ws, size_t ws_size,
                              hipStream_t stream)
{
  (void)in_sizes; (void)n_in; (void)out_size;
  const float* x    = (const float*)d_in[0];
  const float* wq   = (const float*)d_in[1];
  const float* wkv  = (const float*)d_in[2];
  const float* hrel = (const float*)d_in[3];
  const float* wrel = (const float*)d_in[4];
  float* out = (float*)d_out;
  unsigned short* qkv = (unsigned short*)d_ws;

  const size_t per_batch = (size_t)HWPIX * MQKV * sizeof(unsigned short); // 25.2 MB
  const int chunk = (ws_size >= 4 * per_batch) ? 4 : 1;

  for (int b0 = 0; b0 < 4; b0 += chunk) {
    dim3 g1(chunk * (HWPIX / 64), MQKV / 64);
    proj_kernel<<<g1, 256, 0, stream>>>(x + (size_t)b0 * CIN * HWPIX, wq, wkv, qkv);
    dim3 g2(256, HEADS, chunk);
    attn_kernel<<<g2, 256, 0, stream>>>(qkv, hrel, wrel, out, b0);
  }
}

// Round 2
// 390.931 us; speedup vs baseline: 2.0542x; 2.0542x over previous
//
#include <hip/hip_runtime.h>
#include <stdint.h>

#define HEADS 8
#define DH    32
#define BSZ   8
#define HALO  3
#define WIN   14
#define NKEY  196
#define NQ    64
#define CIN   256
#define IMG   128
#define HWPIX 16384
#define MQKV  768
#define SCALE 0.17677669529663689f  // 32^-0.5

// LDS strides chosen for 16B alignment + bank spread
#define KS_STRIDE  40    // shorts: 80B rows (16B mult; key*20 mod 32 spreads banks)
#define VT_STRIDE  232   // shorts: 464B rows
#define PQ_STRIDE  232   // shorts
#define RH_STRIDE  65    // floats

typedef short bf16x8 __attribute__((ext_vector_type(8)));
typedef float f32x4  __attribute__((ext_vector_type(4)));

#define AS1 __attribute__((address_space(1)))
#define AS3 __attribute__((address_space(3)))

__device__ __forceinline__ void gl_lds16(const void* g, void* l) {
  __builtin_amdgcn_global_load_lds((AS1 const unsigned int*)g,
                                   (AS3 unsigned int*)l, 16, 0, 0);
}

__device__ __forceinline__ float bflo(unsigned int u){ return __uint_as_float(u << 16); }
__device__ __forceinline__ float bfhi(unsigned int u){ return __uint_as_float(u & 0xffff0000u); }
__device__ __forceinline__ unsigned short f2bf(float f){        // RNE
  unsigned int u = __float_as_uint(f);
  u += 0x7fffu + ((u >> 16) & 1u);
  return (unsigned short)(u >> 16);
}
__device__ __forceinline__ short f2bf_fast(float f){            // round-nearest (ties up)
  unsigned int u = __float_as_uint(f) + 0x8000u;
  return (short)(u >> 16);
}

// ---------------------------------------------------------------------------
// W concat fp32 -> bf16  (768x256)
// ---------------------------------------------------------------------------
__global__ void convw_kernel(const float* __restrict__ wq,
                             const float* __restrict__ wkv,
                             unsigned short* __restrict__ Wb)
{
  int idx = blockIdx.x * 256 + threadIdx.x;      // float4 index, 49152 total
  float4 v = (idx < 16384) ? ((const float4*)wq)[idx]
                           : ((const float4*)wkv)[idx - 16384];
  ushort4 o;
  o.x = f2bf(v.x); o.y = f2bf(v.y); o.z = f2bf(v.z); o.w = f2bf(v.w);
  ((ushort4*)Wb)[idx] = o;
}

// ---------------------------------------------------------------------------
// Phase 1: qkv projection, MFMA bf16.  D[ch][pix] = sum_k Wb[ch][k] * x[k][pix]
// 128x128 tile, 256 threads (4 waves, 2x2 of 64x64), BK=32, 8 K-steps.
// A (Wb) staged bf16 via global_load_lds; B (x) staged fp32 via global_load_lds
// in [k][pix] with 4-dword pad per 2 rows, converted to bf16 at frag assembly.
// Output qkv[pix][768] bf16 (channel-last, for the attention kernel).
// ---------------------------------------------------------------------------
__global__ __launch_bounds__(256)
void proj_kernel(const float* __restrict__ x,            // chunk base [nb][256][16384]
                 const unsigned short* __restrict__ Wb,  // [768][256] bf16
                 unsigned short* __restrict__ qkv)       // [nb*16384][768] bf16
{
  __shared__ unsigned short As[128 * 32];     // [m][k] bf16, 8 KB
  __shared__ float          Bs[4160];         // [k][pix] f32, padded, 16.6 KB

  const int tid  = threadIdx.x;
  const int w    = tid >> 6, lane = tid & 63;
  const int g16  = lane >> 4, l15 = lane & 15;
  const int m0   = blockIdx.x * 128;          // channel tile (0..5)
  const int n0   = blockIdx.y * 128;          // pixel tile (chunk-local)
  const int bl   = n0 >> 14;                  // batch within chunk
  const int pw0  = n0 & 16383;
  const int wm   = w >> 1, wn = w & 1;

  const float* xb = x + ((size_t)bl << 22);   // bl*256*16384

  f32x4 acc[4][4];
  #pragma unroll
  for (int i = 0; i < 4; ++i)
    #pragma unroll
    for (int j = 0; j < 4; ++j) acc[i][j] = (f32x4){0.f,0.f,0.f,0.f};

  for (int kk = 0; kk < 8; ++kk) {
    const int k0 = kk * 32;
    // stage A: 8 chunks of 16 rows x 32 k (1KB each); wave does 2
    #pragma unroll
    for (int c = 0; c < 2; ++c) {
      int ci  = w * 2 + c;
      int row = m0 + ci * 16 + (lane >> 2);
      gl_lds16(Wb + (size_t)row * 256 + k0 + (lane & 3) * 8,
               (void*)(As + ci * 512));
    }
    // stage B: 16 chunks of 2 k-rows x 128 pix (1KB each); wave does 4
    #pragma unroll
    for (int c = 0; c < 4; ++c) {
      int bi = w * 4 + c;
      int kr = k0 + 2 * bi + (lane >> 5);
      gl_lds16(xb + (size_t)kr * HWPIX + pw0 + (lane & 31) * 4,
               (void*)(Bs + bi * 260));
    }
    __syncthreads();

    bf16x8 af[4], bfr[4];
    #pragma unroll
    for (int t = 0; t < 4; ++t) {
      int m_local = wm * 64 + t * 16 + l15;
      af[t] = *(const bf16x8*)(As + m_local * 32 + g16 * 8);
    }
    #pragma unroll
    for (int t = 0; t < 4; ++t) {
      int n_local = wn * 64 + t * 16 + l15;
      const float* bp = Bs + g16 * 1040 + n_local;
      bf16x8 v;
      v[0] = f2bf_fast(bp[0]);   v[1] = f2bf_fast(bp[128]);
      v[2] = f2bf_fast(bp[260]); v[3] = f2bf_fast(bp[388]);
      v[4] = f2bf_fast(bp[520]); v[5] = f2bf_fast(bp[648]);
      v[6] = f2bf_fast(bp[780]); v[7] = f2bf_fast(bp[908]);
      bfr[t] = v;
    }
    #pragma unroll
    for (int tm = 0; tm < 4; ++tm)
      #pragma unroll
      for (int tn = 0; tn < 4; ++tn)
        acc[tm][tn] = __builtin_amdgcn_mfma_f32_16x16x32_bf16(
                        af[tm], bfr[tn], acc[tm][tn], 0, 0, 0);
    __syncthreads();
  }

  // epilogue: C-layout col = pixel (l15), rows = 4 consecutive channels
  #pragma unroll
  for (int tm = 0; tm < 4; ++tm)
    #pragma unroll
    for (int tn = 0; tn < 4; ++tn) {
      int pix = n0 + wn * 64 + tn * 16 + l15;
      int ch  = m0 + wm * 64 + tm * 16 + g16 * 4;
      f32x4 c = acc[tm][tn];
      ushort4 o;
      o.x = f2bf(c[0]); o.y = f2bf(c[1]); o.z = f2bf(c[2]); o.w = f2bf(c[3]);
      *(ushort4*)(qkv + (size_t)pix * MQKV + ch) = o;
    }
}

// ---------------------------------------------------------------------------
// Phase 2: fused halo attention, MFMA bf16.
// Block = (window, head, batch), 4 waves; wave w owns queries [16w,16w+16).
// S^T = K.Q^T  (C cols = queries) -> exp -> P stored [q][key] bf16 per wave
// O^T = V^T.P^T (C cols = queries) -> normalize by this lane's own row sum.
// ---------------------------------------------------------------------------
__global__ __launch_bounds__(256)
void attn_kernel(const unsigned short* __restrict__ qkv, // chunk base [nb*16384][768]
                 const float* __restrict__ hrel,         // [27][32]
                 const float* __restrict__ wrel,         // [27][32]
                 float* __restrict__ out,                // [4][256][128][128]
                 int b0)
{
  __shared__ unsigned short Ks[208 * KS_STRIDE];      // 16640 B, [key][dh]
  __shared__ unsigned short Vt[32 * VT_STRIDE];       // 14848 B, [dh][key]
  __shared__ unsigned short Pq[4 * 16 * PQ_STRIDE];   // 29696 B, per-wave [q][key]
  __shared__ float RhS[15 * RH_STRIDE];               // [ky][q] (+1 guard row)
  __shared__ float RwS[14 * RH_STRIDE];               // [kx][q]

  const int tid = threadIdx.x;
  const int by = blockIdx.x >> 4, bx = blockIdx.x & 15;
  const int hd = blockIdx.y, bb = blockIdx.z;
  const size_t pixbase = (size_t)bb * HWPIX;

  // ---- zero pads ----
  for (int i = tid; i < 12 * 5; i += 256)            // Ks keys 196..207
    *(uint4*)(Ks + (196 + i / 5) * KS_STRIDE + (i % 5) * 8) = make_uint4(0,0,0,0);
  for (int i = tid; i < 32 * 28; i += 256) {         // Vt cols 196..223
    int dh = i / 28, c = 196 + i % 28;
    Vt[dh * VT_STRIDE + c] = 0;
  }
  if (tid < 128)                                     // Pq cols 208..223 (64 rows)
    *(uint4*)(Pq + (tid >> 1) * PQ_STRIDE + 208 + (tid & 1) * 8) = make_uint4(0,0,0,0);

  // ---- stage K (natural) and V (transposed) ----
  for (int idx = tid; idx < NKEY * 8; idx += 256) {
    int key = idx >> 3, part = idx & 7;
    int ky = key / WIN, kx = key - ky * WIN;
    int sy = by * BSZ - HALO + ky, sx = bx * BSZ - HALO + kx;
    uint4 val = make_uint4(0, 0, 0, 0);
    if (sy >= 0 && sy < IMG && sx >= 0 && sx < IMG)
      val = *(const uint4*)(qkv + (pixbase + sy * IMG + sx) * MQKV + CIN + hd * 64 + part * 8);
    if (part < 4) {
      *(uint4*)(Ks + key * KS_STRIDE + part * 8) = val;
    } else {
      int dh0 = (part - 4) * 8;
      unsigned int u[4] = {val.x, val.y, val.z, val.w};
      #pragma unroll
      for (int e = 0; e < 4; ++e) {
        Vt[(dh0 + 2 * e    ) * VT_STRIDE + key] = (unsigned short)(u[e] & 0xffffu);
        Vt[(dh0 + 2 * e + 1) * VT_STRIDE + key] = (unsigned short)(u[e] >> 16);
      }
    }
  }

  // ---- bias tables Rh[ky][q], Rw[kx][q] ----
  for (int idx = tid; idx < NQ * WIN; idx += 256) {
    int q = idx & 63, j = idx >> 6;
    int qy = q >> 3, qx = q & 7;
    const unsigned short* qp =
        qkv + (pixbase + (size_t)(by * BSZ + qy) * IMG + bx * BSZ + qx) * MQKV + hd * DH;
    float qf[32];
    #pragma unroll
    for (int i = 0; i < 4; ++i) {
      uint4 u = ((const uint4*)qp)[i];
      qf[i*8+0] = bflo(u.x); qf[i*8+1] = bfhi(u.x);
      qf[i*8+2] = bflo(u.y); qf[i*8+3] = bfhi(u.y);
      qf[i*8+4] = bflo(u.z); qf[i*8+5] = bfhi(u.z);
      qf[i*8+6] = bflo(u.w); qf[i*8+7] = bfhi(u.w);
    }
    const float* hr = hrel + (j - qy + WIN - 1) * DH;
    const float* wr = wrel + (j - qx + WIN - 1) * DH;
    float dh_ = 0.f, dw_ = 0.f;
    #pragma unroll
    for (int d = 0; d < 32; ++d) { dh_ = fmaf(qf[d], hr[d], dh_); dw_ = fmaf(qf[d], wr[d], dw_); }
    RhS[j * RH_STRIDE + q] = dh_;
    RwS[j * RH_STRIDE + q] = dw_;
  }
  __syncthreads();

  // ---- per-wave attention ----
  const int w = tid >> 6, lane = tid & 63;
  const int g16 = lane >> 4, l15 = lane & 15;
  const int q = w * 16 + l15;                       // this lane's query (column)
  const int gy = by * BSZ + (q >> 3), gx = bx * BSZ + (q & 7);

  bf16x8 qf = *(const bf16x8*)(qkv + (pixbase + (size_t)gy * IMG + gx) * MQKV + hd * DH + g16 * 8);

  unsigned short* Pw = Pq + w * 16 * PQ_STRIDE;
  float lsum = 0.f;

  for (int nt = 0; nt < 13; ++nt) {
    bf16x8 kf = *(const bf16x8*)(Ks + (nt * 16 + l15) * KS_STRIDE + g16 * 8);
    f32x4 c = (f32x4){0.f, 0.f, 0.f, 0.f};
    c = __builtin_amdgcn_mfma_f32_16x16x32_bf16(kf, qf, c, 0, 0, 0);
    float pv[4];
    #pragma unroll
    for (int i = 0; i < 4; ++i) {
      int key = nt * 16 + g16 * 4 + i;
      int ky = key / WIN, kx = key - ky * WIN;
      float s = c[i] * SCALE + RhS[ky * RH_STRIDE + q] + RwS[kx * RH_STRIDE + q];
      float p = (key < NKEY) ? __expf(s) : 0.f;
      lsum += p;
      pv[i] = p;
    }
    ushort4 pk;
    pk.x = f2bf(pv[0]); pk.y = f2bf(pv[1]); pk.z = f2bf(pv[2]); pk.w = f2bf(pv[3]);
    *(ushort4*)(Pw + l15 * PQ_STRIDE + nt * 16 + g16 * 4) = pk;
  }

  lsum += __shfl_xor(lsum, 16);
  lsum += __shfl_xor(lsum, 32);
  float inv = 1.f / lsum;

  f32x4 o0 = (f32x4){0.f,0.f,0.f,0.f}, o1 = (f32x4){0.f,0.f,0.f,0.f};
  for (int c7 = 0; c7 < 7; ++c7) {
    bf16x8 pf = *(const bf16x8*)(Pw + l15 * PQ_STRIDE + c7 * 32 + g16 * 8);
    bf16x8 v0 = *(const bf16x8*)(Vt + l15 * VT_STRIDE + c7 * 32 + g16 * 8);
    bf16x8 v1 = *(const bf16x8*)(Vt + (16 + l15) * VT_STRIDE + c7 * 32 + g16 * 8);
    o0 = __builtin_amdgcn_mfma_f32_16x16x32_bf16(v0, pf, o0, 0, 0, 0);
    o1 = __builtin_amdgcn_mfma_f32_16x16x32_bf16(v1, pf, o1, 0, 0, 0);
  }

  float* ob = out + (((size_t)(b0 + bb) * 256 + hd * DH) * HWPIX) + (size_t)gy * IMG + gx;
  #pragma unroll
  for (int i = 0; i < 4; ++i) {
    int dh0 = g16 * 4 + i;
    ob[(size_t)dh0 * HWPIX]        = o0[i] * inv;
    ob[(size_t)(dh0 + 16) * HWPIX] = o1[i] * inv;
  }
}

// ---------------------------------------------------------------------------
extern "C" void kernel_launch(void* const* d_in, const int* in_sizes, int n_in,
                              void* d_out, int out_size, void* d_ws, size_t ws_size,
                              hipStream_t stream)
{
  (void)in_sizes; (void)n_in; (void)out_size;
  const float* x    = (const float*)d_in[0];
  const float* wq   = (const float*)d_in[1];
  const float* wkv  = (const float*)d_in[2];
  const float* hrel = (const float*)d_in[3];
  const float* wrel = (const float*)d_in[4];
  float* out = (float*)d_out;

  unsigned short* Wb  = (unsigned short*)d_ws;                    // 393216 B
  unsigned short* qkv = (unsigned short*)((char*)d_ws + 393216);

  const size_t per_batch = (size_t)HWPIX * MQKV * sizeof(unsigned short); // 25.2 MB
  const int chunk = (ws_size >= 393216 + 4 * per_batch) ? 4 : 1;

  convw_kernel<<<192, 256, 0, stream>>>(wq, wkv, Wb);
  for (int b0 = 0; b0 < 4; b0 += chunk) {
    dim3 g1(6, chunk * 128);
    proj_kernel<<<g1, 256, 0, stream>>>(x + (size_t)b0 * CIN * HWPIX, Wb, qkv);
    dim3 g2(256, HEADS, chunk);
    attn_kernel<<<g2, 256, 0, stream>>>(qkv, hrel, wrel, out, b0);
  }
}

// Round 3
// 348.249 us; speedup vs baseline: 2.3059x; 1.1226x over previous
//
#include <hip/hip_runtime.h>
#include <stdint.h>

#define HEADS 8
#define DH    32
#define BSZ   8
#define HALO  3
#define WIN   14
#define NKEY  196
#define CIN   256
#define IMG   128
#define HWPIX 16384
#define MROW  1216        // 256 q + 512 kv + 448 bias channels
#define MPAD  1280        // M rounded up to 10 tiles of 128
#define SCALE 0.17677669529663689f  // 32^-0.5

#define KS_STRIDE 40      // shorts (20 dw: good spread)
#define VT_STRIDE 228     // shorts (114 dw == 2 mod 4: part-scatter 2-way, reads conflict-free)
#define PQ_STRIDE 120     // shorts (112 keys max per half + pad)
#define RH_STRIDE 65      // floats

typedef short bf16x8 __attribute__((ext_vector_type(8)));
typedef short bf16x4 __attribute__((ext_vector_type(4)));
typedef float f32x4  __attribute__((ext_vector_type(4)));

#define AS1 __attribute__((address_space(1)))
#define AS3 __attribute__((address_space(3)))

__device__ __forceinline__ void gl_lds16(const void* g, void* l) {
  __builtin_amdgcn_global_load_lds((AS1 const unsigned int*)g,
                                   (AS3 unsigned int*)l, 16, 0, 0);
}

__device__ __forceinline__ float bf2f(unsigned short s){ return __uint_as_float(((unsigned int)s) << 16); }
__device__ __forceinline__ unsigned short f2bf(float f){        // RNE
  unsigned int u = __float_as_uint(f);
  u += 0x7fffu + ((u >> 16) & 1u);
  return (unsigned short)(u >> 16);
}

__device__ __forceinline__ bf16x8 ld_vt(const unsigned short* p) {
  bf16x4 a = *(const bf16x4*)p;
  bf16x4 b = *(const bf16x4*)(p + 4);
  bf16x8 r;
  r[0]=a[0]; r[1]=a[1]; r[2]=a[2]; r[3]=a[3];
  r[4]=b[0]; r[5]=b[1]; r[6]=b[2]; r[7]=b[3];
  return r;
}

// ---------------------------------------------------------------------------
// W concat fp32 -> bf16 into Wb rows 0..767
// ---------------------------------------------------------------------------
__global__ void convw_kernel(const float* __restrict__ wq,
                             const float* __restrict__ wkv,
                             unsigned short* __restrict__ Wb)
{
  int idx = blockIdx.x * 256 + threadIdx.x;      // float4 index, 49152 total
  float4 v = (idx < 16384) ? ((const float4*)wq)[idx]
                           : ((const float4*)wkv)[idx - 16384];
  ushort4 o;
  o.x = f2bf(v.x); o.y = f2bf(v.y); o.z = f2bf(v.z); o.w = f2bf(v.w);
  ((ushort4*)Wb)[idx] = o;
}

// ---------------------------------------------------------------------------
// Bias weight rows: Wb[768 + h*56 + t][c] = sum_d wq[(h*32+d)][c] * rel_t[d]
// t<27: height_rel[t]; t in [28,55): width_rel[t-28]; t==27,55: zero pad.
// ---------------------------------------------------------------------------
__global__ void conve_kernel(const float* __restrict__ wq,
                             const float* __restrict__ hrel,
                             const float* __restrict__ wrel,
                             unsigned short* __restrict__ Wb)
{
  int row = blockIdx.x;             // 0..447
  int h = row / 56, t = row % 56;
  int c = threadIdx.x;              // 0..255
  const float* rel = nullptr;
  if (t < 27) rel = hrel + t * 32;
  else if (t >= 28 && t < 55) rel = wrel + (t - 28) * 32;
  float acc = 0.f;
  if (rel) {
    #pragma unroll
    for (int d = 0; d < 32; ++d)
      acc = fmaf(wq[(size_t)(h * 32 + d) * CIN + c], rel[d], acc);
  }
  Wb[(size_t)(768 + row) * CIN + c] = rel ? f2bf(acc) : (unsigned short)0;
}

// ---------------------------------------------------------------------------
// x [chunk][256][16384] f32  ->  xb [chunk][16384][256] bf16 (transpose+convert)
// 64-pixel x 256-channel tiles via LDS.
// ---------------------------------------------------------------------------
__global__ __launch_bounds__(256)
void convx_kernel(const float* __restrict__ x, unsigned short* __restrict__ xb)
{
  __shared__ unsigned short T[64 * 264];     // [pix][ch], rows padded to 264
  const int tid = threadIdx.x;
  const int p0 = blockIdx.x * 64;
  const float* xin = x + (size_t)blockIdx.y * CIN * HWPIX;
  unsigned short* xo = xb + ((size_t)blockIdx.y * HWPIX + p0) * CIN;

  for (int idx = tid; idx < 2048; idx += 256) {
    int cp = idx >> 4, f = idx & 15;         // channel-pair, float4-group
    const float* r0 = xin + (size_t)(2 * cp) * HWPIX + p0 + f * 4;
    float4 a = *(const float4*)r0;
    float4 b = *(const float4*)(r0 + HWPIX);
    unsigned short* tp = T + (4 * f) * 264 + 2 * cp;
    *(unsigned int*)(tp      ) = (unsigned int)f2bf(a.x) | ((unsigned int)f2bf(b.x) << 16);
    *(unsigned int*)(tp + 264) = (unsigned int)f2bf(a.y) | ((unsigned int)f2bf(b.y) << 16);
    *(unsigned int*)(tp + 528) = (unsigned int)f2bf(a.z) | ((unsigned int)f2bf(b.z) << 16);
    *(unsigned int*)(tp + 792) = (unsigned int)f2bf(a.w) | ((unsigned int)f2bf(b.w) << 16);
  }
  __syncthreads();
  for (int idx = tid; idx < 2048; idx += 256) {
    int p = idx >> 5, u = idx & 31;
    *(uint4*)(xo + (size_t)p * CIN + u * 8) = *(const uint4*)(T + p * 264 + u * 8);
  }
}

// ---------------------------------------------------------------------------
// Phase 1: projection GEMM, MFMA bf16, m97-style.
// D[ch][pix] = sum_k Wb[ch][k] * xb[pix][k].  128x128 tile, BK=64, 4 K-steps.
// Both operands staged via global_load_lds width=16; frags are ds_read_b128.
// Store guarded to ch<1216; qkv row = [q 0..255 | kv 256..767 | bias 768..1215].
// ---------------------------------------------------------------------------
__global__ __launch_bounds__(256, 3)
void proj_kernel(const unsigned short* __restrict__ xb,   // [chunk][16384][256] bf16
                 const unsigned short* __restrict__ Wb,   // [1280][256] bf16
                 unsigned short* __restrict__ qkv)        // [chunk*16384][1216] bf16
{
  __shared__ unsigned short As[128 * 64];   // [m][k] 16 KB
  __shared__ unsigned short Bs[128 * 64];   // [pix][k] 16 KB

  const int tid = threadIdx.x;
  const int w = tid >> 6, lane = tid & 63;
  const int g16 = lane >> 4, l15 = lane & 15;
  const int m0 = blockIdx.x * 128;
  const int bl = blockIdx.y >> 7;
  const int p0 = (blockIdx.y & 127) * 128;
  const int wm = w >> 1, wn = w & 1;
  const unsigned short* xrow = xb + ((size_t)bl * HWPIX + p0) * CIN;

  f32x4 acc[4][4];
  #pragma unroll
  for (int i = 0; i < 4; ++i)
    #pragma unroll
    for (int j = 0; j < 4; ++j) acc[i][j] = (f32x4){0.f,0.f,0.f,0.f};

  for (int kk = 0; kk < 4; ++kk) {
    const int k0 = kk * 64;
    #pragma unroll
    for (int c = 0; c < 4; ++c) {           // 1KB chunks: 8 rows x 64 k
      int ci = w * 4 + c;
      gl_lds16(Wb   + (size_t)(m0 + ci*8 + (lane>>3)) * CIN + k0 + (lane&7)*8, As + ci*512);
      gl_lds16(xrow + (size_t)(     ci*8 + (lane>>3)) * CIN + k0 + (lane&7)*8, Bs + ci*512);
    }
    __syncthreads();

    #pragma unroll
    for (int kh = 0; kh < 2; ++kh) {
      bf16x8 af[4], bfr[4];
      #pragma unroll
      for (int t = 0; t < 4; ++t) {
        af[t]  = *(const bf16x8*)(As + (wm*64 + t*16 + l15)*64 + kh*32 + g16*8);
        bfr[t] = *(const bf16x8*)(Bs + (wn*64 + t*16 + l15)*64 + kh*32 + g16*8);
      }
      #pragma unroll
      for (int tm = 0; tm < 4; ++tm)
        #pragma unroll
        for (int tn = 0; tn < 4; ++tn)
          acc[tm][tn] = __builtin_amdgcn_mfma_f32_16x16x32_bf16(
                          af[tm], bfr[tn], acc[tm][tn], 0, 0, 0);
    }
    __syncthreads();
  }

  #pragma unroll
  for (int tm = 0; tm < 4; ++tm) {
    int ch = m0 + wm*64 + tm*16 + g16*4;
    if (ch < MROW) {                         // uniform per (wm,tm): tiles align to 16
      #pragma unroll
      for (int tn = 0; tn < 4; ++tn) {
        int pix = p0 + wn*64 + tn*16 + l15;
        f32x4 c = acc[tm][tn];
        ushort4 o;
        o.x = f2bf(c[0]); o.y = f2bf(c[1]); o.z = f2bf(c[2]); o.w = f2bf(c[3]);
        *(ushort4*)(qkv + ((size_t)bl * HWPIX + pix) * MROW + ch) = o;
      }
    }
  }
}

// ---------------------------------------------------------------------------
// Phase 2: fused halo attention, MFMA bf16, 3 blocks/CU.
// S^T = K.Q^T (C cols = queries) -> exp -> P (wave-private LDS, two key-halves
// 112/96 reusing one buffer) -> O^T = V^T.P^T -> normalize by own row sum.
// Bias logits read from precomputed qkv channels 768+h*56+t.
// ---------------------------------------------------------------------------
__global__ __launch_bounds__(256, 3)
void attn_kernel(const unsigned short* __restrict__ qkv,  // chunk base
                 float* __restrict__ out,                 // [4][256][128][128]
                 int b0)
{
  __shared__ unsigned short Ks[208 * KS_STRIDE];   // 16640 B [key][dh]
  __shared__ unsigned short Vt[32 * VT_STRIDE];    // 14592 B [dh][key]
  __shared__ unsigned short Pq[64 * PQ_STRIDE];    // 15360 B [q][key-in-half]
  __shared__ float RhS[14 * RH_STRIDE];            //  3640 B [ky][q]
  __shared__ float RwS[14 * RH_STRIDE];            //  3640 B [kx][q]

  const int tid = threadIdx.x;
  const int by = blockIdx.x >> 4, bx = blockIdx.x & 15;
  const int hd = blockIdx.y, bb = blockIdx.z;
  const size_t pixbase = (size_t)bb * HWPIX;

  // zero pads (keys 196..207)
  for (int i = tid; i < 60; i += 256)
    *(uint4*)(Ks + (196 + i / 5) * KS_STRIDE + (i % 5) * 8) = make_uint4(0,0,0,0);
  for (int i = tid; i < 384; i += 256)
    Vt[(i & 31) * VT_STRIDE + 196 + (i >> 5)] = 0;

  // stage K (natural) and V (transposed)
  for (int idx = tid; idx < NKEY * 8; idx += 256) {
    int key = idx >> 3, part = idx & 7;
    int ky = key / WIN, kx = key - ky * WIN;
    int sy = by * BSZ - HALO + ky, sx = bx * BSZ - HALO + kx;
    uint4 val = make_uint4(0,0,0,0);
    if (sy >= 0 && sy < IMG && sx >= 0 && sx < IMG)
      val = *(const uint4*)(qkv + (pixbase + sy * IMG + sx) * MROW + CIN + hd * 64 + part * 8);
    if (part < 4) {
      *(uint4*)(Ks + key * KS_STRIDE + part * 8) = val;
    } else {
      int dh0 = (part - 4) * 8;
      unsigned int u[4] = {val.x, val.y, val.z, val.w};
      #pragma unroll
      for (int e = 0; e < 4; ++e) {
        Vt[(dh0 + 2*e    ) * VT_STRIDE + key] = (unsigned short)(u[e] & 0xffffu);
        Vt[(dh0 + 2*e + 1) * VT_STRIDE + key] = (unsigned short)(u[e] >> 16);
      }
    }
  }

  // bias tables from precomputed channels (scalar loads, L2/L3-hot)
  for (int idx = tid; idx < 1792; idx += 256) {
    int q = idx & 63, r = idx >> 6;            // r 0..27
    int qy = q >> 3, qx = q & 7;
    const unsigned short* bp =
        qkv + (pixbase + (size_t)(by * BSZ + qy) * IMG + bx * BSZ + qx) * MROW + 768 + hd * 56;
    if (r < 14) RhS[r * RH_STRIDE + q]        = bf2f(bp[r - qy + 13]);
    else        RwS[(r - 14) * RH_STRIDE + q] = bf2f(bp[28 + (r - 14) - qx + 13]);
  }
  __syncthreads();

  // per-wave attention
  const int w = tid >> 6, lane = tid & 63;
  const int g16 = lane >> 4, l15 = lane & 15;
  const int q = w * 16 + l15;
  const int gy = by * BSZ + (q >> 3), gx = bx * BSZ + (q & 7);

  bf16x8 qf = *(const bf16x8*)(qkv + (pixbase + (size_t)gy * IMG + gx) * MROW + hd * DH + g16 * 8);
  unsigned short* Prow = Pq + q * PQ_STRIDE;

  float lsum = 0.f;
  f32x4 o0 = (f32x4){0.f,0.f,0.f,0.f}, o1 = (f32x4){0.f,0.f,0.f,0.f};

  #pragma unroll
  for (int half = 0; half < 2; ++half) {
    const int t0 = half ? 7 : 0;
    const int ntiles = half ? 6 : 7;
    for (int u = 0; u < ntiles; ++u) {
      int nt = t0 + u;
      bf16x8 kf = *(const bf16x8*)(Ks + (nt * 16 + l15) * KS_STRIDE + g16 * 8);
      f32x4 c = (f32x4){0.f,0.f,0.f,0.f};
      c = __builtin_amdgcn_mfma_f32_16x16x32_bf16(kf, qf, c, 0, 0, 0);
      float pv[4];
      #pragma unroll
      for (int i = 0; i < 4; ++i) {
        int key = nt * 16 + g16 * 4 + i;
        int ky = key / WIN, kx = key - ky * WIN;
        int ky2 = ky < 14 ? ky : 13;
        float s = c[i] * SCALE + RhS[ky2 * RH_STRIDE + q] + RwS[kx * RH_STRIDE + q];
        float p = (key < NKEY) ? __expf(s) : 0.f;
        lsum += p;
        pv[i] = p;
      }
      ushort4 pk;
      pk.x = f2bf(pv[0]); pk.y = f2bf(pv[1]); pk.z = f2bf(pv[2]); pk.w = f2bf(pv[3]);
      *(ushort4*)(Prow + u * 16 + g16 * 4) = pk;
    }
    // PV over this half (wave-private Pq: same-wave DS ordering, no barrier)
    const int nch = half ? 3 : 4;
    for (int cc = 0; cc < nch; ++cc) {
      bf16x8 pf = (bf16x8){0,0,0,0,0,0,0,0};
      bool masked = (half == 0 && cc == 3);       // keys 96..127: only 96..111 real
      if (!masked || g16 < 2)
        pf = *(const bf16x8*)(Prow + cc * 32 + g16 * 8);
      int vcol = (half ? 112 : 0) + cc * 32 + g16 * 8;
      bf16x8 v0 = ld_vt(Vt + l15 * VT_STRIDE + vcol);
      bf16x8 v1 = ld_vt(Vt + (16 + l15) * VT_STRIDE + vcol);
      o0 = __builtin_amdgcn_mfma_f32_16x16x32_bf16(v0, pf, o0, 0, 0, 0);
      o1 = __builtin_amdgcn_mfma_f32_16x16x32_bf16(v1, pf, o1, 0, 0, 0);
    }
  }

  lsum += __shfl_xor(lsum, 16);
  lsum += __shfl_xor(lsum, 32);
  float inv = 1.f / lsum;

  float* ob = out + (((size_t)(b0 + bb) * 256 + hd * DH) * HWPIX) + (size_t)gy * IMG + gx;
  #pragma unroll
  for (int i = 0; i < 4; ++i) {
    int dh0 = g16 * 4 + i;
    ob[(size_t)dh0 * HWPIX]        = o0[i] * inv;
    ob[(size_t)(dh0 + 16) * HWPIX] = o1[i] * inv;
  }
}

// ---------------------------------------------------------------------------
extern "C" void kernel_launch(void* const* d_in, const int* in_sizes, int n_in,
                              void* d_out, int out_size, void* d_ws, size_t ws_size,
                              hipStream_t stream)
{
  (void)in_sizes; (void)n_in; (void)out_size;
  const float* x    = (const float*)d_in[0];
  const float* wq   = (const float*)d_in[1];
  const float* wkv  = (const float*)d_in[2];
  const float* hrel = (const float*)d_in[3];
  const float* wrel = (const float*)d_in[4];
  float* out = (float*)d_out;

  const size_t wb_bytes   = (size_t)MPAD * CIN * 2;      // 655360
  const size_t xb_per_b   = (size_t)HWPIX * CIN * 2;     // 8.39 MB
  const size_t qkv_per_b  = (size_t)HWPIX * MROW * 2;    // 39.85 MB
  const int chunk = (ws_size >= wb_bytes + 4 * (xb_per_b + qkv_per_b)) ? 4 : 1;

  unsigned short* Wb  = (unsigned short*)d_ws;
  unsigned short* xb  = (unsigned short*)((char*)d_ws + wb_bytes);
  unsigned short* qkv = (unsigned short*)((char*)d_ws + wb_bytes + (size_t)chunk * xb_per_b);

  convw_kernel<<<192, 256, 0, stream>>>(wq, wkv, Wb);
  conve_kernel<<<448, 256, 0, stream>>>(wq, hrel, wrel, Wb);

  for (int b0 = 0; b0 < 4; b0 += chunk) {
    convx_kernel<<<dim3(256, chunk), 256, 0, stream>>>(x + (size_t)b0 * CIN * HWPIX, xb);
    proj_kernel<<<dim3(10, 128 * chunk), 256, 0, stream>>>(xb, Wb, qkv);
    attn_kernel<<<dim3(256, HEADS, chunk), 256, 0, stream>>>(qkv, out, b0);
  }
}

// Round 4
// 272.644 us; speedup vs baseline: 2.9454x; 1.2773x over previous
//
#include <hip/hip_runtime.h>
#include <stdint.h>

#define HEADS 8
#define DH    32
#define BSZ   8
#define HALO  3
#define WIN   14
#define NKEY  196
#define CIN   256
#define IMG   128
#define HWPIX 16384
#define MQKV  768         // 8 heads x (q32 + k32 + v32), head-blocked
#define SCALE 0.17677669529663689f  // 32^-0.5

#define KS_STRIDE 36      // shorts, 72 B rows (8B aligned, l15*18dw: 16 distinct banks)
#define VT_STRIDE 212     // shorts (106 dw == 2 mod 4; reads conflict-free)
#define PQ_STRIDE 120     // shorts (16B-mult rows; q*60dw -> 2-way max)
#define QB_STRIDE 68      // shorts (8B-mult; q*34dw -> 16 distinct banks)

typedef short bf16x8 __attribute__((ext_vector_type(8)));
typedef short bf16x4 __attribute__((ext_vector_type(4)));
typedef float f32x4  __attribute__((ext_vector_type(4)));

#define AS1 __attribute__((address_space(1)))
#define AS3 __attribute__((address_space(3)))

__device__ __forceinline__ void gl_lds16(const void* g, void* l) {
  __builtin_amdgcn_global_load_lds((AS1 const unsigned int*)g,
                                   (AS3 unsigned int*)l, 16, 0, 0);
}

__device__ __forceinline__ float bf2f(unsigned short s){ return __uint_as_float(((unsigned int)s) << 16); }
__device__ __forceinline__ unsigned short f2bf(float f){        // RNE
  unsigned int u = __float_as_uint(f);
  u += 0x7fffu + ((u >> 16) & 1u);
  return (unsigned short)(u >> 16);
}

// 8-short fragment from two 8B-aligned LDS halves
__device__ __forceinline__ bf16x8 ld2(const unsigned short* p) {
  bf16x4 a = *(const bf16x4*)p;
  bf16x4 b = *(const bf16x4*)(p + 4);
  bf16x8 r;
  r[0]=a[0]; r[1]=a[1]; r[2]=a[2]; r[3]=a[3];
  r[4]=b[0]; r[5]=b[1]; r[6]=b[2]; r[7]=b[3];
  return r;
}

__device__ __forceinline__ void st_bf4(unsigned short* p, f32x4 c) {
  ushort4 o;
  o.x = f2bf(c[0]); o.y = f2bf(c[1]); o.z = f2bf(c[2]); o.w = f2bf(c[3]);
  *(ushort4*)p = o;
}

// ---------------------------------------------------------------------------
// W fp32 -> bf16, head-blocked rows: m = h*96 + d; d<32 -> wq[h*32+d],
// d in [32,96) -> wkv[h*64 + d-32].
// ---------------------------------------------------------------------------
__global__ void convw_kernel(const float* __restrict__ wq,
                             const float* __restrict__ wkv,
                             unsigned short* __restrict__ Wb)
{
  int idx = blockIdx.x * 256 + threadIdx.x;      // 768 rows x 64 float4
  int m = idx >> 6, c4 = idx & 63;
  int h = m / 96, d = m - h * 96;
  const float* src = (d < 32) ? wq  + (size_t)(h * 32 + d) * CIN
                              : wkv + (size_t)(h * 64 + d - 32) * CIN;
  float4 v = *(const float4*)(src + c4 * 4);
  ushort4 o;
  o.x = f2bf(v.x); o.y = f2bf(v.y); o.z = f2bf(v.z); o.w = f2bf(v.w);
  *(ushort4*)(Wb + (size_t)m * CIN + c4 * 4) = o;
}

// ---------------------------------------------------------------------------
// rel tables -> bf16 [64][32]: rows 0..26 hrel, 27..31 zero, 32..58 wrel, 59..63 zero
// ---------------------------------------------------------------------------
__global__ void convrel_kernel(const float* __restrict__ hrel,
                               const float* __restrict__ wrel,
                               unsigned short* __restrict__ relb)
{
  int idx = blockIdx.x * 256 + threadIdx.x;      // 2048
  int r = idx >> 5, c = idx & 31;
  float v = 0.f;
  if (r < 27) v = hrel[r * 32 + c];
  else if (r >= 32 && r < 59) v = wrel[(r - 32) * 32 + c];
  relb[idx] = f2bf(v);
}

// ---------------------------------------------------------------------------
// x [chunk][256][16384] f32 -> xb [chunk][16384][256] bf16
// ---------------------------------------------------------------------------
__global__ __launch_bounds__(256)
void convx_kernel(const float* __restrict__ x, unsigned short* __restrict__ xb)
{
  __shared__ unsigned short T[64 * 264];
  const int tid = threadIdx.x;
  const int p0 = blockIdx.x * 64;
  const float* xin = x + (size_t)blockIdx.y * CIN * HWPIX;
  unsigned short* xo = xb + ((size_t)blockIdx.y * HWPIX + p0) * CIN;

  for (int idx = tid; idx < 2048; idx += 256) {
    int cp = idx >> 4, f = idx & 15;
    const float* r0 = xin + (size_t)(2 * cp) * HWPIX + p0 + f * 4;
    float4 a = *(const float4*)r0;
    float4 b = *(const float4*)(r0 + HWPIX);
    unsigned short* tp = T + (4 * f) * 264 + 2 * cp;
    *(unsigned int*)(tp      ) = (unsigned int)f2bf(a.x) | ((unsigned int)f2bf(b.x) << 16);
    *(unsigned int*)(tp + 264) = (unsigned int)f2bf(a.y) | ((unsigned int)f2bf(b.y) << 16);
    *(unsigned int*)(tp + 528) = (unsigned int)f2bf(a.z) | ((unsigned int)f2bf(b.z) << 16);
    *(unsigned int*)(tp + 792) = (unsigned int)f2bf(a.w) | ((unsigned int)f2bf(b.w) << 16);
  }
  __syncthreads();
  for (int idx = tid; idx < 2048; idx += 256) {
    int p = idx >> 5, u = idx & 31;
    *(uint4*)(xo + (size_t)p * CIN + u * 8) = *(const uint4*)(T + p * 264 + u * 8);
  }
}

// ---------------------------------------------------------------------------
// Phase 1: projection GEMM, MFMA bf16 (m97-style). M=768 exactly 6 tiles.
// ---------------------------------------------------------------------------
__global__ __launch_bounds__(256, 3)
void proj_kernel(const unsigned short* __restrict__ xb,   // [chunk][16384][256]
                 const unsigned short* __restrict__ Wb,   // [768][256]
                 unsigned short* __restrict__ qkv)        // [chunk*16384][768]
{
  __shared__ unsigned short As[128 * 64];
  __shared__ unsigned short Bs[128 * 64];

  const int tid = threadIdx.x;
  const int w = tid >> 6, lane = tid & 63;
  const int g16 = lane >> 4, l15 = lane & 15;
  const int m0 = blockIdx.x * 128;
  const int bl = blockIdx.y >> 7;
  const int p0 = (blockIdx.y & 127) * 128;
  const int wm = w >> 1, wn = w & 1;
  const unsigned short* xrow = xb + ((size_t)bl * HWPIX + p0) * CIN;

  f32x4 acc[4][4];
  #pragma unroll
  for (int i = 0; i < 4; ++i)
    #pragma unroll
    for (int j = 0; j < 4; ++j) acc[i][j] = (f32x4){0.f,0.f,0.f,0.f};

  for (int kk = 0; kk < 4; ++kk) {
    const int k0 = kk * 64;
    #pragma unroll
    for (int c = 0; c < 4; ++c) {
      int ci = w * 4 + c;
      gl_lds16(Wb   + (size_t)(m0 + ci*8 + (lane>>3)) * CIN + k0 + (lane&7)*8, As + ci*512);
      gl_lds16(xrow + (size_t)(     ci*8 + (lane>>3)) * CIN + k0 + (lane&7)*8, Bs + ci*512);
    }
    __syncthreads();

    #pragma unroll
    for (int kh = 0; kh < 2; ++kh) {
      bf16x8 af[4], bfr[4];
      #pragma unroll
      for (int t = 0; t < 4; ++t) {
        af[t]  = *(const bf16x8*)(As + (wm*64 + t*16 + l15)*64 + kh*32 + g16*8);
        bfr[t] = *(const bf16x8*)(Bs + (wn*64 + t*16 + l15)*64 + kh*32 + g16*8);
      }
      #pragma unroll
      for (int tm = 0; tm < 4; ++tm)
        #pragma unroll
        for (int tn = 0; tn < 4; ++tn)
          acc[tm][tn] = __builtin_amdgcn_mfma_f32_16x16x32_bf16(
                          af[tm], bfr[tn], acc[tm][tn], 0, 0, 0);
    }
    __syncthreads();
  }

  #pragma unroll
  for (int tm = 0; tm < 4; ++tm) {
    int ch = m0 + wm*64 + tm*16 + g16*4;
    #pragma unroll
    for (int tn = 0; tn < 4; ++tn) {
      int pix = p0 + wn*64 + tn*16 + l15;
      st_bf4(qkv + ((size_t)bl * HWPIX + pix) * MQKV + ch, acc[tm][tn]);
    }
  }
}

// ---------------------------------------------------------------------------
// Phase 2: fused halo attention, MFMA bf16, 3 blocks/CU (52608 B LDS).
// Bias computed in-kernel via 4 MFMAs from relb (staged transiently in Pq).
// ---------------------------------------------------------------------------
__global__ __launch_bounds__(256, 3)
void attn_kernel(const unsigned short* __restrict__ qkv,  // chunk base
                 const unsigned short* __restrict__ relb, // [64][32] bf16
                 float* __restrict__ out,                 // [4][256][128][128]
                 int b0)
{
  __shared__ unsigned short Ks[208 * KS_STRIDE];   // 14976 B [key][dh]
  __shared__ unsigned short Vt[32 * VT_STRIDE];    // 13568 B [dh][key]
  __shared__ unsigned short Pq[64 * PQ_STRIDE];    // 15360 B [q][key-in-half] (first 4KB = relb transient)
  __shared__ unsigned short QB[64 * QB_STRIDE];    //  8704 B [q][t_h 0..31 | t_w 32..63]

  const int tid = threadIdx.x;
  const int by = blockIdx.x >> 4, bx = blockIdx.x & 15;
  const int hd = blockIdx.y, bb = blockIdx.z;
  const size_t pixbase = (size_t)bb * HWPIX;

  const int w = tid >> 6, lane = tid & 63;
  const int g16 = lane >> 4, l15 = lane & 15;
  const int q = w * 16 + l15;
  const int qy = q >> 3, qx = q & 7;
  const int gy = by * BSZ + qy, gx = bx * BSZ + qx;

  // own q fragment (B-operand for both bias and QK MFMAs)
  bf16x8 qf = *(const bf16x8*)(qkv + (pixbase + (size_t)gy * IMG + gx) * MQKV + hd * 96 + g16 * 8);

  // relb -> Pq[0..2047]
  *(uint4*)(Pq + tid * 8) = *(const uint4*)(relb + tid * 8);

  // zero pads: Ks rows 196..207 (contiguous 432 shorts), Vt cols 196..211
  for (int i = tid; i < 432; i += 256) Ks[196 * KS_STRIDE + i] = 0;
  for (int i = tid; i < 512; i += 256) Vt[(i >> 4) * VT_STRIDE + 196 + (i & 15)] = 0;

  // stage K (rows, b64 pairs) and V (transposed scatter)
  for (int idx = tid; idx < NKEY * 8; idx += 256) {
    int key = idx >> 3, part = idx & 7;
    int ky = key / WIN, kx = key - ky * WIN;
    int sy = by * BSZ - HALO + ky, sx = bx * BSZ - HALO + kx;
    uint4 val = make_uint4(0,0,0,0);
    if ((unsigned)sy < (unsigned)IMG && (unsigned)sx < (unsigned)IMG)
      val = *(const uint4*)(qkv + (pixbase + sy * IMG + sx) * MQKV + hd * 96 + 32 + part * 8);
    if (part < 4) {
      unsigned short* kp = Ks + key * KS_STRIDE + part * 8;
      *(unsigned long long*)(kp    ) = (unsigned long long)val.x | ((unsigned long long)val.y << 32);
      *(unsigned long long*)(kp + 4) = (unsigned long long)val.z | ((unsigned long long)val.w << 32);
    } else {
      int dh0 = (part - 4) * 8;
      unsigned int u[4] = {val.x, val.y, val.z, val.w};
      #pragma unroll
      for (int e = 0; e < 4; ++e) {
        Vt[(dh0 + 2*e    ) * VT_STRIDE + key] = (unsigned short)(u[e] & 0xffffu);
        Vt[(dh0 + 2*e + 1) * VT_STRIDE + key] = (unsigned short)(u[e] >> 16);
      }
    }
  }
  __syncthreads();

  // ---- bias via MFMA: C[t][q] = rel[t] . q ----
  {
    const unsigned short* Hb = Pq;
    const unsigned short* Wr = Pq + 1024;
    bf16x8 ah0 = *(const bf16x8*)(Hb + l15 * 32 + g16 * 8);
    bf16x8 ah1 = *(const bf16x8*)(Hb + (16 + l15) * 32 + g16 * 8);
    bf16x8 aw0 = *(const bf16x8*)(Wr + l15 * 32 + g16 * 8);
    bf16x8 aw1 = *(const bf16x8*)(Wr + (16 + l15) * 32 + g16 * 8);
    f32x4 z = (f32x4){0.f,0.f,0.f,0.f};
    f32x4 ch0 = __builtin_amdgcn_mfma_f32_16x16x32_bf16(ah0, qf, z, 0, 0, 0);
    f32x4 ch1 = __builtin_amdgcn_mfma_f32_16x16x32_bf16(ah1, qf, z, 0, 0, 0);
    f32x4 cw0 = __builtin_amdgcn_mfma_f32_16x16x32_bf16(aw0, qf, z, 0, 0, 0);
    f32x4 cw1 = __builtin_amdgcn_mfma_f32_16x16x32_bf16(aw1, qf, z, 0, 0, 0);
    unsigned short* QBq = QB + q * QB_STRIDE;
    st_bf4(QBq      + g16 * 4, ch0);
    st_bf4(QBq + 16 + g16 * 4, ch1);
    st_bf4(QBq + 32 + g16 * 4, cw0);
    st_bf4(QBq + 48 + g16 * 4, cw1);
  }
  __syncthreads();   // all waves done reading relb region before Pq P-writes

  const unsigned short* QBq = QB + q * QB_STRIDE;
  unsigned short* Prow = Pq + q * PQ_STRIDE;

  float lsum = 0.f;
  f32x4 o0 = (f32x4){0.f,0.f,0.f,0.f}, o1 = (f32x4){0.f,0.f,0.f,0.f};
  const f32x4 z = (f32x4){0.f,0.f,0.f,0.f};

  #pragma unroll
  for (int half = 0; half < 2; ++half) {
    const int t0 = half ? 7 : 0;
    const int ntiles = half ? 6 : 7;
    #pragma unroll
    for (int u = 0; u < ntiles; ++u) {
      int nt = t0 + u;
      bf16x8 kf = ld2(Ks + (nt * 16 + l15) * KS_STRIDE + g16 * 8);
      f32x4 c = __builtin_amdgcn_mfma_f32_16x16x32_bf16(kf, qf, z, 0, 0, 0);
      float pv[4];
      #pragma unroll
      for (int i = 0; i < 4; ++i) {
        int key = nt * 16 + g16 * 4 + i;
        int ky = key / WIN, kx = key - ky * WIN;
        float s = c[i] * SCALE + bf2f(QBq[ky - qy + 13]) + bf2f(QBq[32 + kx - qx + 13]);
        float p = (key < NKEY) ? __expf(s) : 0.f;
        lsum += p;
        pv[i] = p;
      }
      ushort4 pk;
      pk.x = f2bf(pv[0]); pk.y = f2bf(pv[1]); pk.z = f2bf(pv[2]); pk.w = f2bf(pv[3]);
      *(ushort4*)(Prow + u * 16 + g16 * 4) = pk;
    }
    const int nch = half ? 3 : 4;
    #pragma unroll
    for (int cc = 0; cc < nch; ++cc) {
      bf16x8 pf = (bf16x8){0,0,0,0,0,0,0,0};
      bool masked = (half == 0 && cc == 3);     // keys 96..127: only 96..111 real
      if (!masked || g16 < 2)
        pf = *(const bf16x8*)(Prow + cc * 32 + g16 * 8);
      int vcol = (half ? 112 : 0) + cc * 32 + g16 * 8;
      bf16x8 v0 = ld2(Vt + l15 * VT_STRIDE + vcol);
      bf16x8 v1 = ld2(Vt + (16 + l15) * VT_STRIDE + vcol);
      o0 = __builtin_amdgcn_mfma_f32_16x16x32_bf16(v0, pf, o0, 0, 0, 0);
      o1 = __builtin_amdgcn_mfma_f32_16x16x32_bf16(v1, pf, o1, 0, 0, 0);
    }
  }

  lsum += __shfl_xor(lsum, 16);
  lsum += __shfl_xor(lsum, 32);
  float inv = 1.f / lsum;

  float* ob = out + (((size_t)(b0 + bb) * 256 + hd * DH) * HWPIX) + (size_t)gy * IMG + gx;
  #pragma unroll
  for (int i = 0; i < 4; ++i) {
    int dh0 = g16 * 4 + i;
    ob[(size_t)dh0 * HWPIX]        = o0[i] * inv;
    ob[(size_t)(dh0 + 16) * HWPIX] = o1[i] * inv;
  }
}

// ---------------------------------------------------------------------------
extern "C" void kernel_launch(void* const* d_in, const int* in_sizes, int n_in,
                              void* d_out, int out_size, void* d_ws, size_t ws_size,
                              hipStream_t stream)
{
  (void)in_sizes; (void)n_in; (void)out_size;
  const float* x    = (const float*)d_in[0];
  const float* wq   = (const float*)d_in[1];
  const float* wkv  = (const float*)d_in[2];
  const float* hrel = (const float*)d_in[3];
  const float* wrel = (const float*)d_in[4];
  float* out = (float*)d_out;

  const size_t wb_bytes   = (size_t)MQKV * CIN * 2;      // 393216
  const size_t relb_bytes = 4096;
  const size_t xb_per_b   = (size_t)HWPIX * CIN * 2;     // 8.39 MB
  const size_t qkv_per_b  = (size_t)HWPIX * MQKV * 2;    // 25.2 MB
  const int chunk = (ws_size >= wb_bytes + relb_bytes + 4 * (xb_per_b + qkv_per_b)) ? 4 : 1;

  unsigned short* Wb   = (unsigned short*)d_ws;
  unsigned short* relb = (unsigned short*)((char*)d_ws + wb_bytes);
  unsigned short* xb   = (unsigned short*)((char*)d_ws + wb_bytes + relb_bytes);
  unsigned short* qkv  = (unsigned short*)((char*)d_ws + wb_bytes + relb_bytes
                                           + (size_t)chunk * xb_per_b);

  convw_kernel<<<192, 256, 0, stream>>>(wq, wkv, Wb);
  convrel_kernel<<<8, 256, 0, stream>>>(hrel, wrel, relb);

  for (int b0 = 0; b0 < 4; b0 += chunk) {
    convx_kernel<<<dim3(256, chunk), 256, 0, stream>>>(x + (size_t)b0 * CIN * HWPIX, xb);
    proj_kernel<<<dim3(6, 128 * chunk), 256, 0, stream>>>(xb, Wb, qkv);
    attn_kernel<<<dim3(256, HEADS, chunk), 256, 0, stream>>>(qkv, relb, out, b0);
  }
}